// Round 1
// baseline (307.601 us; speedup 1.0000x reference)
//
#include <hip/hip_runtime.h>
#include <hip/hip_bf16.h>

// Flash-attention fwd for B=2,S=2048,H=16,D=128, logits = QK^T / D (no sqrt).
// Grid (S/BQ, B*H), 512 threads = 8 waves; wave w owns Q rows [w*16, w*16+16).
// bf16 MFMA 16x16x32; K row-major in LDS, V transposed in LDS, P via LDS
// round-trip (C-layout -> A-layout).

#define SEQ   2048
#define NHEAD 16
#define DH    128
#define NB    2
#define BQ    128
#define BK    64
#define NWAVE 8
#define NTHR  (NWAVE * 64)
#define KSTR  136   // bf16 elems; 272 B row stride (16B aligned, bank-safe)
#define VSTR  72    // 144 B row stride
#define PSTR  72
#define NKV   (SEQ / BK)

typedef __attribute__((ext_vector_type(8))) short bf16x8;
typedef __attribute__((ext_vector_type(4))) float f32x4;

__device__ __forceinline__ unsigned short f2bf(float x) {
    // RNE fp32 -> bf16 (inputs are finite; no NaN handling needed)
    unsigned int u = __builtin_bit_cast(unsigned int, x);
    u += 0x7fffu + ((u >> 16) & 1u);
    return (unsigned short)(u >> 16);
}

__global__ __launch_bounds__(NTHR, 4) void attn_fwd(
    const float* __restrict__ Q, const float* __restrict__ K,
    const float* __restrict__ V, float* __restrict__ O)
{
    __shared__ unsigned short Kl[BK * KSTR];        // K tile, row-major
    __shared__ unsigned short Vt[DH * VSTR];        // V tile, transposed [d][k]
    __shared__ unsigned short Pl[NWAVE * 16 * PSTR];// per-wave P round-trip

    const int tid  = threadIdx.x;
    const int wave = tid >> 6;
    const int lane = tid & 63;
    const int quad = lane >> 4;   // 0..3
    const int l16  = lane & 15;

    const int b  = blockIdx.y >> 4;
    const int h  = blockIdx.y & 15;
    const int q0 = blockIdx.x * BQ;

    const size_t rowstride = (size_t)NHEAD * DH;    // 2048 floats between seq rows
    const float* qbase = Q + (size_t)b * SEQ * rowstride + (size_t)h * DH;
    const float* kbase = K + (size_t)b * SEQ * rowstride + (size_t)h * DH;
    const float* vbase = V + (size_t)b * SEQ * rowstride + (size_t)h * DH;

    // ---- Q fragments (A layout: m = l16, k = quad*8 + j), once per kernel
    bf16x8 qf[4];
    {
        const float* qp = qbase + (size_t)(q0 + wave * 16 + l16) * rowstride;
        #pragma unroll
        for (int c = 0; c < 4; ++c) {
            const float* p = qp + c * 32 + quad * 8;
            float4 x0 = *(const float4*)p;
            float4 x1 = *(const float4*)(p + 4);
            bf16x8 f;
            f[0] = (short)f2bf(x0.x); f[1] = (short)f2bf(x0.y);
            f[2] = (short)f2bf(x0.z); f[3] = (short)f2bf(x0.w);
            f[4] = (short)f2bf(x1.x); f[5] = (short)f2bf(x1.y);
            f[6] = (short)f2bf(x1.z); f[7] = (short)f2bf(x1.w);
            qf[c] = f;
        }
    }

    const f32x4 fzero = {0.f, 0.f, 0.f, 0.f};
    f32x4 o[8];                       // 16 x 128 output, C layout per 16-col tile
    #pragma unroll
    for (int t = 0; t < 8; ++t) o[t] = fzero;
    float m2[4]   = {-INFINITY, -INFINITY, -INFINITY, -INFINITY}; // log2-space max
    float lsum[4] = {0.f, 0.f, 0.f, 0.f};                          // lane-partial

    const float c1 = 1.44269504088896340736f / 128.0f;  // log2(e)/D

    for (int kv = 0; kv < NKV; ++kv) {
        const int k0 = kv * BK;

        // ---- stage K tile [BK x DH] -> bf16 row-major
        {
            const int r  = tid >> 5;   // 0..15
            const int c4 = tid & 31;   // float4 column
            #pragma unroll
            for (int p = 0; p < 4; ++p) {
                const int row = p * 16 + r;
                float4 x = *(const float4*)(kbase + (size_t)(k0 + row) * rowstride + c4 * 4);
                ushort4 pk;
                pk.x = f2bf(x.x); pk.y = f2bf(x.y);
                pk.z = f2bf(x.z); pk.w = f2bf(x.w);
                *(ushort4*)&Kl[row * KSTR + c4 * 4] = pk;
            }
        }
        // ---- stage V tile transposed -> Vt[d][k]
        {
            const int kk   = tid & 63;   // kv row
            const int dblk = tid >> 6;   // 0..7 -> d block of 16
            const float* src = vbase + (size_t)(k0 + kk) * rowstride + dblk * 16;
            #pragma unroll
            for (int j = 0; j < 4; ++j) {
                float4 x = *(const float4*)(src + j * 4);
                const int d = dblk * 16 + j * 4;
                Vt[(d + 0) * VSTR + kk] = f2bf(x.x);
                Vt[(d + 1) * VSTR + kk] = f2bf(x.y);
                Vt[(d + 2) * VSTR + kk] = f2bf(x.z);
                Vt[(d + 3) * VSTR + kk] = f2bf(x.w);
            }
        }
        __syncthreads();

        // ---- S = Q K^T : per wave 16 x BK, 4 col-tiles x 4 k-chunks
        f32x4 s[4];
        #pragma unroll
        for (int t = 0; t < 4; ++t) s[t] = fzero;
        #pragma unroll
        for (int c = 0; c < 4; ++c) {
            #pragma unroll
            for (int t = 0; t < 4; ++t) {
                bf16x8 kf = *(const bf16x8*)&Kl[(t * 16 + l16) * KSTR + c * 32 + quad * 8];
                s[t] = __builtin_amdgcn_mfma_f32_16x16x32_bf16(qf[c], kf, s[t], 0, 0, 0);
            }
        }

        // ---- online softmax; C layout: row = quad*4+r, col = t*16+l16
        #pragma unroll
        for (int r = 0; r < 4; ++r) {
            float mx = fmaxf(fmaxf(s[0][r], s[1][r]), fmaxf(s[2][r], s[3][r]));
            mx = fmaxf(mx, __shfl_xor(mx, 1, 64));
            mx = fmaxf(mx, __shfl_xor(mx, 2, 64));
            mx = fmaxf(mx, __shfl_xor(mx, 4, 64));
            mx = fmaxf(mx, __shfl_xor(mx, 8, 64));
            const float mnew  = fmaxf(m2[r], mx * c1);
            const float alpha = exp2f(m2[r] - mnew);   // first iter: exp2(-inf)=0
            m2[r] = mnew;
            float psum = 0.f;
            const int prow = wave * 16 + quad * 4 + r;
            #pragma unroll
            for (int t = 0; t < 4; ++t) {
                float pv = exp2f(s[t][r] * c1 - mnew);
                psum += pv;
                Pl[prow * PSTR + t * 16 + l16] = f2bf(pv);
            }
            lsum[r] = lsum[r] * alpha + psum;
            #pragma unroll
            for (int t = 0; t < 8; ++t) o[t][r] *= alpha;
        }

        // ---- O += P V  (P wave-private in LDS; V as B-operand from Vt)
        #pragma unroll
        for (int kc = 0; kc < BK / 32; ++kc) {
            bf16x8 pf = *(const bf16x8*)&Pl[(wave * 16 + l16) * PSTR + kc * 32 + quad * 8];
            #pragma unroll
            for (int t = 0; t < 8; ++t) {
                bf16x8 vf = *(const bf16x8*)&Vt[(t * 16 + l16) * VSTR + kc * 32 + quad * 8];
                o[t] = __builtin_amdgcn_mfma_f32_16x16x32_bf16(pf, vf, o[t], 0, 0, 0);
            }
        }
        __syncthreads();
    }

    // ---- epilogue: reduce l across the quad's 16 lanes, normalize, store
    #pragma unroll
    for (int r = 0; r < 4; ++r) {
        float l = lsum[r];
        l += __shfl_xor(l, 1, 64);
        l += __shfl_xor(l, 2, 64);
        l += __shfl_xor(l, 4, 64);
        l += __shfl_xor(l, 8, 64);
        const float inv = 1.0f / l;
        const int row = q0 + wave * 16 + quad * 4 + r;
        float* dst = O + (size_t)(b * SEQ + row) * rowstride + (size_t)h * DH;
        #pragma unroll
        for (int t = 0; t < 8; ++t)
            dst[t * 16 + l16] = o[t][r] * inv;
    }
}

extern "C" void kernel_launch(void* const* d_in, const int* in_sizes, int n_in,
                              void* d_out, int out_size, void* d_ws, size_t ws_size,
                              hipStream_t stream) {
    const float* q = (const float*)d_in[0];
    const float* k = (const float*)d_in[1];
    const float* v = (const float*)d_in[2];
    float* o = (float*)d_out;
    dim3 grid(SEQ / BQ, NB * NHEAD);
    attn_fwd<<<grid, dim3(NTHR), 0, stream>>>(q, k, v, o);
}